// Round 22
// baseline (156.302 us; speedup 1.0000x reference)
//
#include <hip/hip_runtime.h>
#include <hip/hip_bf16.h>

// ---------------------------------------------------------------------------
// GAT encoder, 2 layers. Round 22: round-21 pipeline + 2-node-interleaved
// gather (each wave processes two nodes concurrently -> steady 16 rows in
// flight; tails share waves). 8 dispatches.
// ---------------------------------------------------------------------------

#define NEG_SLOPE 0.2f
#define NB 416          // hist/scatter blocks (>= CU count)
#define EPB 2048        // edges per block; NB*EPB = 851968 >= E+N
#define NBUCKET 1568    // buckets of 32 dsts
#define BSH 5

typedef __attribute__((ext_vector_type(8))) short bf16x8;
typedef __attribute__((ext_vector_type(4))) float f32x4;

__device__ __forceinline__ unsigned short f2bf(float v) {
    __hip_bfloat16 b = __float2bfloat16(v);
    return *reinterpret_cast<unsigned short*>(&b);
}
__device__ __forceinline__ float bf2f(unsigned short u) {
    __hip_bfloat16 b = *reinterpret_cast<__hip_bfloat16*>(&u);
    return __bfloat162float(b);
}

// ---- K1: blocks [0,NB): LDS bucket histogram. [NB,NB+256): W transposes.
//      [NB+256,NB+288): W1 projection dots. ----
__global__ __launch_bounds__(256) void hist_wprep_k(
    const int* __restrict__ dstE, const float* __restrict__ W1,
    const float* __restrict__ W2, const float* __restrict__ a_src1,
    const float* __restrict__ a_dst1, int* __restrict__ histG,
    unsigned short* __restrict__ w1T, unsigned short* __restrict__ w2T,
    float* __restrict__ w_s1, float* __restrict__ w_d1, int E, int N) {
    const int b = blockIdx.x;
    if (b < NB) {
        __shared__ int h[NBUCKET];
        for (int i = threadIdx.x; i < NBUCKET; i += 256) h[i] = 0;
        __syncthreads();
        const int base = b * EPB;
        const int total = E + N;
        #pragma unroll
        for (int q = 0; q < EPB / 256; ++q) {
            int i = base + q * 256 + threadIdx.x;
            if (i < total) {
                int di = (i < E) ? dstE[i] : i - E;
                atomicAdd(&h[di >> BSH], 1);
            }
        }
        __syncthreads();
        for (int i = threadIdx.x; i < NBUCKET; i += 256)
            histG[b * NBUCKET + i] = h[i];
    } else if (b < NB + 128) {           // W1[128][256] -> w1T[256][128]
        int i = (b - NB) * 256 + threadIdx.x;
        int k = i >> 8, n = i & 255;
        w1T[n * 128 + k] = f2bf(W1[i]);
    } else if (b < NB + 256) {           // W2[256][128] -> w2T[128][256]
        int j = (b - NB - 128) * 256 + threadIdx.x;
        int k = j >> 7, n = j & 127;
        w2T[n * 256 + k] = f2bf(W2[j]);
    } else {                             // projection dots
        int w = ((b - NB - 256) * 256 + threadIdx.x) >> 6;  // 0..127
        int lane = threadIdx.x & 63;
        const float* row = W1 + (size_t)w * 256;
        float ss = 0.f, dd = 0.f;
        #pragma unroll
        for (int f = lane; f < 256; f += 64) {
            float v = row[f];
            ss += v * a_src1[f];
            dd += v * a_dst1[f];
        }
        #pragma unroll
        for (int off = 32; off; off >>= 1) {
            ss += __shfl_down(ss, off);
            dd += __shfl_down(dd, off);
        }
        if (lane == 0) { w_s1[w] = ss; w_d1[w] = dd; }
    }
}

// ---- K2: blocks [0, NBUCKET/4): per-bucket column scan. rest: xprep. ----
__global__ __launch_bounds__(256) void colscan_xprep_k(
    int* __restrict__ histG, int* __restrict__ colSum,
    const float* __restrict__ x, const float* __restrict__ va,
    const float* __restrict__ vb, unsigned short* __restrict__ xbf,
    float* __restrict__ s, float* __restrict__ d, int N) {
    const int b = blockIdx.x;
    constexpr int CSB = NBUCKET / 4;   // 392
    if (b < CSB) {
        const int bkt = b * 4 + (threadIdx.x >> 6);
        const int l = threadIdx.x & 63;
        int carry = 0;
        #pragma unroll
        for (int c = 0; c < (NB + 63) / 64; ++c) {
            int blk = c * 64 + l;
            int v = (blk < NB) ? histG[blk * NBUCKET + bkt] : 0;
            int incl = v;
            #pragma unroll
            for (int off = 1; off < 64; off <<= 1) {
                int t = __shfl_up(incl, off);
                if (l >= off) incl += t;
            }
            if (blk < NB) histG[blk * NBUCKET + bkt] = carry + (incl - v);
            carry += __shfl(incl, 63);
        }
        if (l == 0) colSum[bkt] = carry;
    } else {
        int w = (((b - CSB) * 256) + threadIdx.x) >> 6;
        int lane = threadIdx.x & 63;
        if (w >= N) return;
        float2 v = *(const float2*)(x + (size_t)w * 128 + lane * 2);
        ushort2 u;
        u.x = f2bf(v.x);
        u.y = f2bf(v.y);
        *(ushort2*)(xbf + (size_t)w * 128 + lane * 2) = u;
        float ss = v.x * va[lane * 2] + v.y * va[lane * 2 + 1];
        float dd = v.x * vb[lane * 2] + v.y * vb[lane * 2 + 1];
        #pragma unroll
        for (int off = 32; off; off >>= 1) {
            ss += __shfl_down(ss, off);
            dd += __shfl_down(dd, off);
        }
        if (lane == 0) { s[w] = ss; d[w] = dd; }
    }
}

// ---- K3: scatter packed (dst<<16|src) into bucket-grouped order. ----
__global__ __launch_bounds__(256) void bscatter_k(
    const int* __restrict__ srcE, const int* __restrict__ dstE,
    const int* __restrict__ histG, const int* __restrict__ colSum,
    unsigned* __restrict__ packed, int E, int N) {
    __shared__ int bb_s[NBUCKET];
    __shared__ int cur[NBUCKET];
    __shared__ int wsum[4];
    const int tid = threadIdx.x;
    {
        const int lane = tid & 63, wv = tid >> 6;
        const int base = tid * 7;   // 256*7 >= NBUCKET
        int loc[7];
        int ssum = 0;
        #pragma unroll
        for (int q = 0; q < 7; ++q) {
            int idx = base + q;
            int c = (idx < NBUCKET) ? colSum[idx] : 0;
            loc[q] = ssum;
            ssum += c;
        }
        int incl = ssum;
        #pragma unroll
        for (int off = 1; off < 64; off <<= 1) {
            int t = __shfl_up(incl, off);
            if (lane >= off) incl += t;
        }
        if (lane == 63) wsum[wv] = incl;
        __syncthreads();
        if (tid == 0) {
            int r = 0;
            #pragma unroll
            for (int i = 0; i < 4; ++i) { int c = wsum[i]; wsum[i] = r; r += c; }
        }
        __syncthreads();
        const int b0 = wsum[wv] + (incl - ssum);
        #pragma unroll
        for (int q = 0; q < 7; ++q) {
            int idx = base + q;
            if (idx < NBUCKET) bb_s[idx] = b0 + loc[q];
        }
    }
    for (int i = tid; i < NBUCKET; i += 256) cur[i] = 0;
    __syncthreads();
    const int b = blockIdx.x;
    const int base = b * EPB;
    const int total = E + N;
    #pragma unroll
    for (int q = 0; q < EPB / 256; ++q) {
        int i = base + q * 256 + tid;
        if (i < total) {
            int di, si;
            if (i < E) { di = dstE[i]; si = srcE[i]; }
            else       { di = si = i - E; }
            int bk = di >> BSH;
            int r = atomicAdd(&cur[bk], 1);
            packed[bb_s[bk] + histG[b * NBUCKET + bk] + r] =
                ((unsigned)di << 16) | (unsigned)si;
        }
    }
}

// ---- K4: per-bucket LDS counting sort; writes u16 ssrc + rowptr. ----
__global__ __launch_bounds__(256) void bsort_k(
    const unsigned* __restrict__ packed, const int* __restrict__ colSum,
    unsigned short* __restrict__ ssrc, int* __restrict__ rowptr,
    int EA, int N) {
    __shared__ unsigned arr[2048];
    __shared__ int cnt[32], pf[32], cur[32];
    __shared__ int red[4];
    __shared__ int beg_s;
    const int b = blockIdx.x;
    const int tid = threadIdx.x;
    {
        int part = 0;
        for (int i = tid; i < b; i += 256) part += colSum[i];
        #pragma unroll
        for (int off = 32; off; off >>= 1) part += __shfl_down(part, off);
        if ((tid & 63) == 0) red[tid >> 6] = part;
        __syncthreads();
        if (tid == 0) beg_s = red[0] + red[1] + red[2] + red[3];
    }
    if (tid < 32) cnt[tid] = 0;
    __syncthreads();
    const int beg = beg_s;
    const int L = colSum[b];
    for (int t = tid; t < L; t += 256) {
        unsigned e = packed[beg + t];
        arr[t] = e;
        atomicAdd(&cnt[(e >> 16) & 31], 1);
    }
    __syncthreads();
    if (tid == 0) {
        int r = 0;
        #pragma unroll
        for (int j = 0; j < 32; ++j) { pf[j] = r; cur[j] = r; r += cnt[j]; }
    }
    __syncthreads();
    if (tid < 32) {
        int dd = b * 32 + tid;
        if (dd < N) rowptr[dd] = beg + pf[tid];
    }
    for (int t = tid; t < L; t += 256) {
        unsigned e = arr[t];
        int r = atomicAdd(&cur[(e >> 16) & 31], 1);
        ssrc[beg + r] = (unsigned short)(e & 0xffffu);
    }
    if (b == 0 && tid == 0) rowptr[N] = EA;
}

// ---- bf16 MFMA GEMM, BM=128 BN=128 BK=32 (unchanged) ----
template <int K, int NN, int EPI>
__global__ __launch_bounds__(256) void gemm_bf16(
    const unsigned short* __restrict__ A, const unsigned short* __restrict__ BT,
    unsigned short* __restrict__ C, const float* __restrict__ bias,
    const float* __restrict__ va, const float* __restrict__ vb,
    float* __restrict__ sOut, float* __restrict__ dOut, int M) {
    constexpr int BK = 32, PAD = 8;
    __shared__ short As[128][BK + PAD];
    __shared__ short Bs[128][BK + PAD];
    const int tid = threadIdx.x;
    const int wv = tid >> 6;
    const int ln = tid & 63;
    const int row0 = blockIdx.x * 128;
    const int col0 = blockIdx.y * 128;

    f32x4 acc[2][8];
    #pragma unroll
    for (int m = 0; m < 2; ++m)
        #pragma unroll
        for (int n = 0; n < 8; ++n) acc[m][n] = {0.f, 0.f, 0.f, 0.f};

    const int l15 = ln & 15;
    const int kg = (ln >> 4) * 8;

    for (int k0 = 0; k0 < K; k0 += BK) {
        #pragma unroll
        for (int t = 0; t < 2; ++t) {
            int v = tid + t * 256;
            int r = v >> 2;
            int kc = (v & 3) * 8;
            bf16x8 val = {0, 0, 0, 0, 0, 0, 0, 0};
            int gr = row0 + r;
            if (gr < M)
                val = *(const bf16x8*)(A + (size_t)gr * K + k0 + kc);
            *(bf16x8*)(&As[r][kc]) = val;
        }
        #pragma unroll
        for (int t = 0; t < 2; ++t) {
            int v = tid + t * 256;
            int c = v >> 2;
            int kc = (v & 3) * 8;
            *(bf16x8*)(&Bs[c][kc]) =
                *(const bf16x8*)(BT + (size_t)(col0 + c) * K + k0 + kc);
        }
        __syncthreads();

        bf16x8 ah[2], bh[8];
        #pragma unroll
        for (int m = 0; m < 2; ++m)
            ah[m] = *(const bf16x8*)&As[wv * 32 + m * 16 + l15][kg];
        #pragma unroll
        for (int n = 0; n < 8; ++n)
            bh[n] = *(const bf16x8*)&Bs[n * 16 + l15][kg];
        #pragma unroll
        for (int m = 0; m < 2; ++m)
            #pragma unroll
            for (int n = 0; n < 8; ++n)
                acc[m][n] = __builtin_amdgcn_mfma_f32_16x16x32_bf16(
                    ah[m], bh[n], acc[m][n], 0, 0, 0);
        __syncthreads();
    }

    const int crow = (ln >> 4) * 4;
    #pragma unroll
    for (int m = 0; m < 2; ++m) {
        #pragma unroll
        for (int q = 0; q < 4; ++q) {
            int gr = row0 + wv * 32 + m * 16 + crow + q;
            if (gr >= M) continue;
            if constexpr (EPI == 1) {
                #pragma unroll
                for (int n = 0; n < 8; ++n) {
                    int gc = col0 + n * 16 + l15;
                    float v = acc[m][n][q] + bias[gc];
                    v = fmaxf(v, 0.f);
                    C[(size_t)gr * NN + gc] = f2bf(v);
                }
            } else {
                float sp = 0.f, dp = 0.f;
                #pragma unroll
                for (int n = 0; n < 8; ++n) {
                    int gc = n * 16 + l15;
                    float v = acc[m][n][q];
                    C[(size_t)gr * NN + gc] = f2bf(v);
                    sp += v * va[gc];
                    dp += v * vb[gc];
                }
                #pragma unroll
                for (int off = 1; off < 16; off <<= 1) {
                    sp += __shfl_xor(sp, off);
                    dp += __shfl_xor(dp, off);
                }
                if (l15 == 0) { sOut[gr] = sp; dOut[gr] = dp; }
            }
        }
    }
}

// ---- 2-node-interleaved softmax + weighted gather. One wave per 2 nodes,
// 8 groups x 8 lanes; each iteration issues 8 edges of A + 8 of B (steady
// 16 rows in flight). No max pass. OUTBF: bf16 out; else f32+bias. ----
template <bool OUTBF>
__global__ __launch_bounds__(256) void node_gather_k(
    const int* __restrict__ rowptr, const unsigned short* __restrict__ ssrc,
    const float* __restrict__ s, const float* __restrict__ d,
    const unsigned short* __restrict__ hsrc, const float* __restrict__ bias,
    unsigned short* __restrict__ obf, float* __restrict__ outf, int N) {
    constexpr int F = 128, G = 8;
    const int wv = threadIdx.x >> 6;
    const int lane = threadIdx.x & 63;
    const int nodeA = blockIdx.x * 8 + wv * 2;
    const int nodeB = nodeA + 1;
    if (nodeA >= N) return;
    const bool hasB = (nodeB < N);
    const int begA = rowptr[nodeA];
    const int endA = rowptr[nodeA + 1];
    const int begB = hasB ? rowptr[nodeB] : 0;
    const int endB = hasB ? rowptr[nodeB + 1] : 0;
    const float dnA = d[nodeA];
    const float dnB = hasB ? d[nodeB] : 0.f;
    const int grp = lane >> 3;
    const int lr = lane & 7;

    float accA[16] = {}, accB[16] = {};
    float zsA = 0.f, zsB = 0.f;
    const int cntA = endA - begA;
    const int cntB = endB - begB;
    const int maxIt = (max(cntA, cntB) + G - 1) / G;
    for (int it = 0; it < maxIt; ++it) {
        const int jA = begA + grp + it * G;
        const int jB = begB + grp + it * G;
        const bool vA = jA < endA;
        const bool vB = jB < endB;
        int sjA = vA ? (int)ssrc[jA] : 0;
        int sjB = vB ? (int)ssrc[jB] : 0;
        float eA = s[sjA] + dnA;
        float eB = s[sjB] + dnB;
        const unsigned short* rA = hsrc + (size_t)sjA * F + lr * 16;
        const unsigned short* rB = hsrc + (size_t)sjB * F + lr * 16;
        bf16x8 vA0 = *(const bf16x8*)rA;
        bf16x8 vA1 = *(const bf16x8*)(rA + 8);
        bf16x8 vB0 = *(const bf16x8*)rB;
        bf16x8 vB1 = *(const bf16x8*)(rB + 8);
        eA = (eA > 0.f) ? eA : NEG_SLOPE * eA;
        eB = (eB > 0.f) ? eB : NEG_SLOPE * eB;
        float xA = vA ? __expf(eA) : 0.f;
        float xB = vB ? __expf(eB) : 0.f;
        zsA += xA;
        zsB += xB;
        #pragma unroll
        for (int q = 0; q < 8; ++q) {
            accA[q]     += xA * bf2f(((unsigned short*)&vA0)[q]);
            accA[q + 8] += xA * bf2f(((unsigned short*)&vA1)[q]);
            accB[q]     += xB * bf2f(((unsigned short*)&vB0)[q]);
            accB[q + 8] += xB * bf2f(((unsigned short*)&vB1)[q]);
        }
    }
    #pragma unroll
    for (int off = 8; off < 64; off <<= 1) {
        zsA += __shfl_xor(zsA, off);
        zsB += __shfl_xor(zsB, off);
        #pragma unroll
        for (int q = 0; q < 16; ++q) {
            accA[q] += __shfl_xor(accA[q], off);
            accB[q] += __shfl_xor(accB[q], off);
        }
    }
    // lanes 0-7 write node A; lanes 8-15 write node B (each lane holds the
    // fully reduced sums for its lr = lane & 7)
    if (lane < 8) {
        const float inv = 1.f / zsA;
        if constexpr (OUTBF) {
            bf16x8 w0, w1;
            #pragma unroll
            for (int q = 0; q < 8; ++q) {
                ((unsigned short*)&w0)[q] = f2bf(accA[q] * inv);
                ((unsigned short*)&w1)[q] = f2bf(accA[q + 8] * inv);
            }
            *(bf16x8*)(obf + (size_t)nodeA * F + lr * 16) = w0;
            *(bf16x8*)(obf + (size_t)nodeA * F + lr * 16 + 8) = w1;
        } else {
            float o[16];
            #pragma unroll
            for (int q = 0; q < 16; ++q)
                o[q] = accA[q] * inv + bias[lr * 16 + q];
            float* op = outf + (size_t)nodeA * F + lr * 16;
            *(float4*)op = {o[0], o[1], o[2], o[3]};
            *(float4*)(op + 4) = {o[4], o[5], o[6], o[7]};
            *(float4*)(op + 8) = {o[8], o[9], o[10], o[11]};
            *(float4*)(op + 12) = {o[12], o[13], o[14], o[15]};
        }
    } else if (lane < 16 && hasB) {
        const float inv = 1.f / zsB;
        if constexpr (OUTBF) {
            bf16x8 w0, w1;
            #pragma unroll
            for (int q = 0; q < 8; ++q) {
                ((unsigned short*)&w0)[q] = f2bf(accB[q] * inv);
                ((unsigned short*)&w1)[q] = f2bf(accB[q + 8] * inv);
            }
            *(bf16x8*)(obf + (size_t)nodeB * F + lr * 16) = w0;
            *(bf16x8*)(obf + (size_t)nodeB * F + lr * 16 + 8) = w1;
        } else {
            float o[16];
            #pragma unroll
            for (int q = 0; q < 16; ++q)
                o[q] = accB[q] * inv + bias[lr * 16 + q];
            float* op = outf + (size_t)nodeB * F + lr * 16;
            *(float4*)op = {o[0], o[1], o[2], o[3]};
            *(float4*)(op + 4) = {o[4], o[5], o[6], o[7]};
            *(float4*)(op + 8) = {o[8], o[9], o[10], o[11]};
            *(float4*)(op + 12) = {o[12], o[13], o[14], o[15]};
        }
    }
}

extern "C" void kernel_launch(void* const* d_in, const int* in_sizes, int n_in,
                              void* d_out, int out_size, void* d_ws, size_t ws_size,
                              hipStream_t stream) {
    const float* x      = (const float*)d_in[0];
    const int*   eidx   = (const int*)d_in[1];
    const float* W1     = (const float*)d_in[2];
    const float* a_src1 = (const float*)d_in[3];
    const float* a_dst1 = (const float*)d_in[4];
    const float* b1     = (const float*)d_in[5];
    const float* W2     = (const float*)d_in[6];
    const float* a_src2 = (const float*)d_in[7];
    const float* a_dst2 = (const float*)d_in[8];
    const float* b2     = (const float*)d_in[9];

    const int N = in_sizes[0] / 128;   // 50000
    const int E = in_sizes[1] / 2;     // 800000
    const int F_IN = 128, H = 256, F_OUT = 128;
    const int EA = E + N;

    const int* srcE = eidx;
    const int* dstE = eidx + E;

    // ---- workspace layout ----
    unsigned short* xbf    = (unsigned short*)d_ws;                 // N*128 bf16
    unsigned short* aggx   = xbf + (size_t)N * F_IN;                // N*128 bf16
    unsigned short* g1     = aggx + (size_t)N * F_IN;               // N*256 bf16
    unsigned short* h2bf   = g1 + (size_t)N * H;                    // N*128 bf16
    float*          sbuf   = (float*)(h2bf + (size_t)N * F_OUT);    // N
    float*          dbuf   = sbuf + N;                              // N
    float*          w_s1   = dbuf + N;                              // 128
    float*          w_d1   = w_s1 + F_IN;                           // 128
    unsigned short* w1T    = (unsigned short*)(w_d1 + F_IN);        // 256*128
    unsigned short* w2T    = w1T + 32768;                           // 128*256
    int*            rowptr = (int*)(w2T + 32768);                   // N+1
    int*            histG  = rowptr + (N + 1);                      // NB*NBUCKET
    int*            colSum = histG + NB * NBUCKET;                  // NBUCKET
    unsigned short* ssrc   = (unsigned short*)(colSum + NBUCKET);   // E+N u16
    unsigned*       packed = (unsigned*)(ssrc + ((EA + 1) & ~1));   // E+N u32

    float* out = (float*)d_out;
    const int xblocks = (N * 64 + 255) / 256;   // 12500

    // 1) bucket histograms + weight prep
    hist_wprep_k<<<NB + 288, 256, 0, stream>>>(
        dstE, W1, W2, a_src1, a_dst1, histG, w1T, w2T, w_s1, w_d1, E, N);
    // 2) column scan + xprep
    colscan_xprep_k<<<NBUCKET / 4 + xblocks, 256, 0, stream>>>(
        histG, colSum, x, w_s1, w_d1, xbf, sbuf, dbuf, N);
    // 3) scatter into bucket-grouped order
    bscatter_k<<<NB, 256, 0, stream>>>(srcE, dstE, histG, colSum, packed, E, N);
    // 4) per-bucket counting sort -> u16 ssrc + rowptr
    bsort_k<<<NBUCKET, 256, 0, stream>>>(packed, colSum, ssrc, rowptr, EA, N);

    // 5) layer-1 gather (2 nodes/wave, 8 nodes/block)
    {
        int nb = (N + 7) / 8;
        node_gather_k<true><<<nb, 256, 0, stream>>>(
            rowptr, ssrc, sbuf, dbuf, xbf, nullptr, aggx, nullptr, N);
    }
    // 6) GEMM1 (relu+bias epilogue)
    {
        dim3 gg((N + 127) / 128, H / 128);
        gemm_bf16<128, 256, 1><<<gg, 256, 0, stream>>>(
            aggx, w1T, g1, b1, nullptr, nullptr, nullptr, nullptr, N);
    }
    // 7) GEMM2 (+ in-epilogue layer-2 rowdots)
    {
        dim3 gg((N + 127) / 128, 1);
        gemm_bf16<256, 128, 2><<<gg, 256, 0, stream>>>(
            g1, w2T, h2bf, nullptr, a_src2, a_dst2, sbuf, dbuf, N);
    }
    // 8) layer-2 gather (final output)
    {
        int nb = (N + 7) / 8;
        node_gather_k<false><<<nb, 256, 0, stream>>>(
            rowptr, ssrc, sbuf, dbuf, h2bf, b2, nullptr, out, N);
    }
}

// Round 23
// 145.173 us; speedup vs baseline: 1.0767x; 1.0767x over previous
//
#include <hip/hip_runtime.h>
#include <hip/hip_bf16.h>

// ---------------------------------------------------------------------------
// GAT encoder, 2 layers. Round 23 = round 19 (best measured: 145.6us).
// 8 dispatches: K1 hist+wprep | K2 colscan+xprep | K3 bscatter | K4 bsort |
// gather1 | gemm1 | gemm2 | gather2.
// Rounds 20-22 established: bsort+gather fusion (-parallelism), u16 ssrc
// (null), 2-node interleave (-occupancy) all fail -> gather is at its
// latency-bound floor for this decomposition.
// ---------------------------------------------------------------------------

#define NEG_SLOPE 0.2f
#define NB 416          // hist/scatter blocks (>= CU count)
#define EPB 2048        // edges per block; NB*EPB = 851968 >= E+N
#define NBUCKET 1568    // buckets of 32 dsts
#define BSH 5

typedef __attribute__((ext_vector_type(8))) short bf16x8;
typedef __attribute__((ext_vector_type(4))) float f32x4;

__device__ __forceinline__ unsigned short f2bf(float v) {
    __hip_bfloat16 b = __float2bfloat16(v);
    return *reinterpret_cast<unsigned short*>(&b);
}
__device__ __forceinline__ float bf2f(unsigned short u) {
    __hip_bfloat16 b = *reinterpret_cast<__hip_bfloat16*>(&u);
    return __bfloat162float(b);
}

// ---- K1: blocks [0,NB): LDS bucket histogram. [NB,NB+256): W transposes.
//      [NB+256,NB+288): W1 projection dots. ----
__global__ __launch_bounds__(256) void hist_wprep_k(
    const int* __restrict__ dstE, const float* __restrict__ W1,
    const float* __restrict__ W2, const float* __restrict__ a_src1,
    const float* __restrict__ a_dst1, int* __restrict__ histG,
    unsigned short* __restrict__ w1T, unsigned short* __restrict__ w2T,
    float* __restrict__ w_s1, float* __restrict__ w_d1, int E, int N) {
    const int b = blockIdx.x;
    if (b < NB) {
        __shared__ int h[NBUCKET];
        for (int i = threadIdx.x; i < NBUCKET; i += 256) h[i] = 0;
        __syncthreads();
        const int base = b * EPB;
        const int total = E + N;
        #pragma unroll
        for (int q = 0; q < EPB / 256; ++q) {
            int i = base + q * 256 + threadIdx.x;
            if (i < total) {
                int di = (i < E) ? dstE[i] : i - E;
                atomicAdd(&h[di >> BSH], 1);
            }
        }
        __syncthreads();
        for (int i = threadIdx.x; i < NBUCKET; i += 256)
            histG[b * NBUCKET + i] = h[i];
    } else if (b < NB + 128) {           // W1[128][256] -> w1T[256][128]
        int i = (b - NB) * 256 + threadIdx.x;
        int k = i >> 8, n = i & 255;
        w1T[n * 128 + k] = f2bf(W1[i]);
    } else if (b < NB + 256) {           // W2[256][128] -> w2T[128][256]
        int j = (b - NB - 128) * 256 + threadIdx.x;
        int k = j >> 7, n = j & 127;
        w2T[n * 256 + k] = f2bf(W2[j]);
    } else {                             // projection dots
        int w = ((b - NB - 256) * 256 + threadIdx.x) >> 6;  // 0..127
        int lane = threadIdx.x & 63;
        const float* row = W1 + (size_t)w * 256;
        float ss = 0.f, dd = 0.f;
        #pragma unroll
        for (int f = lane; f < 256; f += 64) {
            float v = row[f];
            ss += v * a_src1[f];
            dd += v * a_dst1[f];
        }
        #pragma unroll
        for (int off = 32; off; off >>= 1) {
            ss += __shfl_down(ss, off);
            dd += __shfl_down(dd, off);
        }
        if (lane == 0) { w_s1[w] = ss; w_d1[w] = dd; }
    }
}

// ---- K2: blocks [0, NBUCKET/4): per-bucket column scan. rest: xprep. ----
__global__ __launch_bounds__(256) void colscan_xprep_k(
    int* __restrict__ histG, int* __restrict__ colSum,
    const float* __restrict__ x, const float* __restrict__ va,
    const float* __restrict__ vb, unsigned short* __restrict__ xbf,
    float* __restrict__ s, float* __restrict__ d, int N) {
    const int b = blockIdx.x;
    constexpr int CSB = NBUCKET / 4;   // 392
    if (b < CSB) {
        const int bkt = b * 4 + (threadIdx.x >> 6);
        const int l = threadIdx.x & 63;
        int carry = 0;
        #pragma unroll
        for (int c = 0; c < (NB + 63) / 64; ++c) {
            int blk = c * 64 + l;
            int v = (blk < NB) ? histG[blk * NBUCKET + bkt] : 0;
            int incl = v;
            #pragma unroll
            for (int off = 1; off < 64; off <<= 1) {
                int t = __shfl_up(incl, off);
                if (l >= off) incl += t;
            }
            if (blk < NB) histG[blk * NBUCKET + bkt] = carry + (incl - v);
            carry += __shfl(incl, 63);
        }
        if (l == 0) colSum[bkt] = carry;
    } else {
        int w = (((b - CSB) * 256) + threadIdx.x) >> 6;
        int lane = threadIdx.x & 63;
        if (w >= N) return;
        float2 v = *(const float2*)(x + (size_t)w * 128 + lane * 2);
        ushort2 u;
        u.x = f2bf(v.x);
        u.y = f2bf(v.y);
        *(ushort2*)(xbf + (size_t)w * 128 + lane * 2) = u;
        float ss = v.x * va[lane * 2] + v.y * va[lane * 2 + 1];
        float dd = v.x * vb[lane * 2] + v.y * vb[lane * 2 + 1];
        #pragma unroll
        for (int off = 32; off; off >>= 1) {
            ss += __shfl_down(ss, off);
            dd += __shfl_down(dd, off);
        }
        if (lane == 0) { s[w] = ss; d[w] = dd; }
    }
}

// ---- K3: scatter packed (dst<<16|src) into bucket-grouped order. ----
__global__ __launch_bounds__(256) void bscatter_k(
    const int* __restrict__ srcE, const int* __restrict__ dstE,
    const int* __restrict__ histG, const int* __restrict__ colSum,
    unsigned* __restrict__ packed, int E, int N) {
    __shared__ int bb_s[NBUCKET];
    __shared__ int cur[NBUCKET];
    __shared__ int wsum[4];
    const int tid = threadIdx.x;
    {
        const int lane = tid & 63, wv = tid >> 6;
        const int base = tid * 7;   // 256*7 >= NBUCKET
        int loc[7];
        int ssum = 0;
        #pragma unroll
        for (int q = 0; q < 7; ++q) {
            int idx = base + q;
            int c = (idx < NBUCKET) ? colSum[idx] : 0;
            loc[q] = ssum;
            ssum += c;
        }
        int incl = ssum;
        #pragma unroll
        for (int off = 1; off < 64; off <<= 1) {
            int t = __shfl_up(incl, off);
            if (lane >= off) incl += t;
        }
        if (lane == 63) wsum[wv] = incl;
        __syncthreads();
        if (tid == 0) {
            int r = 0;
            #pragma unroll
            for (int i = 0; i < 4; ++i) { int c = wsum[i]; wsum[i] = r; r += c; }
        }
        __syncthreads();
        const int b0 = wsum[wv] + (incl - ssum);
        #pragma unroll
        for (int q = 0; q < 7; ++q) {
            int idx = base + q;
            if (idx < NBUCKET) bb_s[idx] = b0 + loc[q];
        }
    }
    for (int i = tid; i < NBUCKET; i += 256) cur[i] = 0;
    __syncthreads();
    const int b = blockIdx.x;
    const int base = b * EPB;
    const int total = E + N;
    #pragma unroll
    for (int q = 0; q < EPB / 256; ++q) {
        int i = base + q * 256 + tid;
        if (i < total) {
            int di, si;
            if (i < E) { di = dstE[i]; si = srcE[i]; }
            else       { di = si = i - E; }
            int bk = di >> BSH;
            int r = atomicAdd(&cur[bk], 1);
            packed[bb_s[bk] + histG[b * NBUCKET + bk] + r] =
                ((unsigned)di << 16) | (unsigned)si;
        }
    }
}

// ---- K4: per-bucket LDS counting sort; beg via block reduce of colSum. ----
__global__ __launch_bounds__(256) void bsort_k(
    const unsigned* __restrict__ packed, const int* __restrict__ colSum,
    int* __restrict__ ssrc, int* __restrict__ rowptr, int EA, int N) {
    __shared__ unsigned arr[2048];
    __shared__ int cnt[32], pf[32], cur[32];
    __shared__ int red[4];
    __shared__ int beg_s;
    const int b = blockIdx.x;
    const int tid = threadIdx.x;
    {
        int part = 0;
        for (int i = tid; i < b; i += 256) part += colSum[i];
        #pragma unroll
        for (int off = 32; off; off >>= 1) part += __shfl_down(part, off);
        if ((tid & 63) == 0) red[tid >> 6] = part;
        __syncthreads();
        if (tid == 0) beg_s = red[0] + red[1] + red[2] + red[3];
    }
    if (tid < 32) cnt[tid] = 0;
    __syncthreads();
    const int beg = beg_s;
    const int L = colSum[b];
    for (int t = tid; t < L; t += 256) {
        unsigned e = packed[beg + t];
        arr[t] = e;
        atomicAdd(&cnt[(e >> 16) & 31], 1);
    }
    __syncthreads();
    if (tid == 0) {
        int r = 0;
        #pragma unroll
        for (int j = 0; j < 32; ++j) { pf[j] = r; cur[j] = r; r += cnt[j]; }
    }
    __syncthreads();
    if (tid < 32) {
        int dd = b * 32 + tid;
        if (dd < N) rowptr[dd] = beg + pf[tid];
    }
    for (int t = tid; t < L; t += 256) {
        unsigned e = arr[t];
        int r = atomicAdd(&cur[(e >> 16) & 31], 1);
        ssrc[beg + r] = (int)(e & 0xffffu);
    }
    if (b == 0 && tid == 0) rowptr[N] = EA;
}

// ---- bf16 MFMA GEMM, BM=128 BN=128 BK=32 ----
template <int K, int NN, int EPI>
__global__ __launch_bounds__(256) void gemm_bf16(
    const unsigned short* __restrict__ A, const unsigned short* __restrict__ BT,
    unsigned short* __restrict__ C, const float* __restrict__ bias,
    const float* __restrict__ va, const float* __restrict__ vb,
    float* __restrict__ sOut, float* __restrict__ dOut, int M) {
    constexpr int BK = 32, PAD = 8;
    __shared__ short As[128][BK + PAD];
    __shared__ short Bs[128][BK + PAD];
    const int tid = threadIdx.x;
    const int wv = tid >> 6;
    const int ln = tid & 63;
    const int row0 = blockIdx.x * 128;
    const int col0 = blockIdx.y * 128;

    f32x4 acc[2][8];
    #pragma unroll
    for (int m = 0; m < 2; ++m)
        #pragma unroll
        for (int n = 0; n < 8; ++n) acc[m][n] = {0.f, 0.f, 0.f, 0.f};

    const int l15 = ln & 15;
    const int kg = (ln >> 4) * 8;

    for (int k0 = 0; k0 < K; k0 += BK) {
        #pragma unroll
        for (int t = 0; t < 2; ++t) {
            int v = tid + t * 256;
            int r = v >> 2;
            int kc = (v & 3) * 8;
            bf16x8 val = {0, 0, 0, 0, 0, 0, 0, 0};
            int gr = row0 + r;
            if (gr < M)
                val = *(const bf16x8*)(A + (size_t)gr * K + k0 + kc);
            *(bf16x8*)(&As[r][kc]) = val;
        }
        #pragma unroll
        for (int t = 0; t < 2; ++t) {
            int v = tid + t * 256;
            int c = v >> 2;
            int kc = (v & 3) * 8;
            *(bf16x8*)(&Bs[c][kc]) =
                *(const bf16x8*)(BT + (size_t)(col0 + c) * K + k0 + kc);
        }
        __syncthreads();

        bf16x8 ah[2], bh[8];
        #pragma unroll
        for (int m = 0; m < 2; ++m)
            ah[m] = *(const bf16x8*)&As[wv * 32 + m * 16 + l15][kg];
        #pragma unroll
        for (int n = 0; n < 8; ++n)
            bh[n] = *(const bf16x8*)&Bs[n * 16 + l15][kg];
        #pragma unroll
        for (int m = 0; m < 2; ++m)
            #pragma unroll
            for (int n = 0; n < 8; ++n)
                acc[m][n] = __builtin_amdgcn_mfma_f32_16x16x32_bf16(
                    ah[m], bh[n], acc[m][n], 0, 0, 0);
        __syncthreads();
    }

    const int crow = (ln >> 4) * 4;
    #pragma unroll
    for (int m = 0; m < 2; ++m) {
        #pragma unroll
        for (int q = 0; q < 4; ++q) {
            int gr = row0 + wv * 32 + m * 16 + crow + q;
            if (gr >= M) continue;
            if constexpr (EPI == 1) {
                #pragma unroll
                for (int n = 0; n < 8; ++n) {
                    int gc = col0 + n * 16 + l15;
                    float v = acc[m][n][q] + bias[gc];
                    v = fmaxf(v, 0.f);
                    C[(size_t)gr * NN + gc] = f2bf(v);
                }
            } else {
                float sp = 0.f, dp = 0.f;
                #pragma unroll
                for (int n = 0; n < 8; ++n) {
                    int gc = n * 16 + l15;
                    float v = acc[m][n][q];
                    C[(size_t)gr * NN + gc] = f2bf(v);
                    sp += v * va[gc];
                    dp += v * vb[gc];
                }
                #pragma unroll
                for (int off = 1; off < 16; off <<= 1) {
                    sp += __shfl_xor(sp, off);
                    dp += __shfl_xor(dp, off);
                }
                if (l15 == 0) { sOut[gr] = sp; dOut[gr] = dp; }
            }
        }
    }
}

// ---- fused softmax + weighted gather. One wave/node, 8 groups x 8 lanes,
// 2-edge unrolled. No max pass (logits bounded; softmax shift-invariant).
// OUTBF: write bf16 (aggx). else: f32 + bias (final output). ----
template <bool OUTBF>
__global__ __launch_bounds__(256) void node_gather_k(
    const int* __restrict__ rowptr, const int* __restrict__ ssrc,
    const float* __restrict__ s, const float* __restrict__ d,
    const unsigned short* __restrict__ hsrc, const float* __restrict__ bias,
    unsigned short* __restrict__ obf, float* __restrict__ outf, int N) {
    constexpr int F = 128, G = 8;
    const int node = blockIdx.x * 4 + (threadIdx.x >> 6);
    const int lane = threadIdx.x & 63;
    if (node >= N) return;
    const int beg = rowptr[node];
    const int end = rowptr[node + 1];
    const float dn = d[node];
    const int grp = lane >> 3;
    const int lr = lane & 7;

    float acc[16] = {};
    float zsum = 0.f;
    int j = beg + grp;
    for (; j + G < end; j += 2 * G) {
        int sj0 = ssrc[j];
        int sj1 = ssrc[j + G];
        float e0 = s[sj0] + dn;
        float e1 = s[sj1] + dn;
        const unsigned short* r0 = hsrc + (size_t)sj0 * F + lr * 16;
        const unsigned short* r1 = hsrc + (size_t)sj1 * F + lr * 16;
        bf16x8 v0a = *(const bf16x8*)r0;
        bf16x8 v0b = *(const bf16x8*)(r0 + 8);
        bf16x8 v1a = *(const bf16x8*)r1;
        bf16x8 v1b = *(const bf16x8*)(r1 + 8);
        e0 = (e0 > 0.f) ? e0 : NEG_SLOPE * e0;
        e1 = (e1 > 0.f) ? e1 : NEG_SLOPE * e1;
        float x0 = __expf(e0);
        float x1 = __expf(e1);
        zsum += x0 + x1;
        #pragma unroll
        for (int q = 0; q < 8; ++q) {
            acc[q]     += x0 * bf2f(((unsigned short*)&v0a)[q]);
            acc[q + 8] += x0 * bf2f(((unsigned short*)&v0b)[q]);
            acc[q]     += x1 * bf2f(((unsigned short*)&v1a)[q]);
            acc[q + 8] += x1 * bf2f(((unsigned short*)&v1b)[q]);
        }
    }
    if (j < end) {
        int sj = ssrc[j];
        float e = s[sj] + dn;
        e = (e > 0.f) ? e : NEG_SLOPE * e;
        float exj = __expf(e);
        zsum += exj;
        const unsigned short* r0 = hsrc + (size_t)sj * F + lr * 16;
        bf16x8 va_ = *(const bf16x8*)r0;
        bf16x8 vb_ = *(const bf16x8*)(r0 + 8);
        #pragma unroll
        for (int q = 0; q < 8; ++q) {
            acc[q]     += exj * bf2f(((unsigned short*)&va_)[q]);
            acc[q + 8] += exj * bf2f(((unsigned short*)&vb_)[q]);
        }
    }
    #pragma unroll
    for (int off = 8; off < 64; off <<= 1) {
        zsum += __shfl_xor(zsum, off);
        #pragma unroll
        for (int q = 0; q < 16; ++q) acc[q] += __shfl_xor(acc[q], off);
    }
    const float inv = 1.f / zsum;

    if (lane < 8) {
        if constexpr (OUTBF) {
            bf16x8 w0, w1;
            #pragma unroll
            for (int q = 0; q < 8; ++q) {
                ((unsigned short*)&w0)[q] = f2bf(acc[q] * inv);
                ((unsigned short*)&w1)[q] = f2bf(acc[q + 8] * inv);
            }
            *(bf16x8*)(obf + (size_t)node * F + lr * 16) = w0;
            *(bf16x8*)(obf + (size_t)node * F + lr * 16 + 8) = w1;
        } else {
            float o[16];
            #pragma unroll
            for (int q = 0; q < 16; ++q)
                o[q] = acc[q] * inv + bias[lr * 16 + q];
            float* op = outf + (size_t)node * F + lr * 16;
            *(float4*)op = {o[0], o[1], o[2], o[3]};
            *(float4*)(op + 4) = {o[4], o[5], o[6], o[7]};
            *(float4*)(op + 8) = {o[8], o[9], o[10], o[11]};
            *(float4*)(op + 12) = {o[12], o[13], o[14], o[15]};
        }
    }
}

extern "C" void kernel_launch(void* const* d_in, const int* in_sizes, int n_in,
                              void* d_out, int out_size, void* d_ws, size_t ws_size,
                              hipStream_t stream) {
    const float* x      = (const float*)d_in[0];
    const int*   eidx   = (const int*)d_in[1];
    const float* W1     = (const float*)d_in[2];
    const float* a_src1 = (const float*)d_in[3];
    const float* a_dst1 = (const float*)d_in[4];
    const float* b1     = (const float*)d_in[5];
    const float* W2     = (const float*)d_in[6];
    const float* a_src2 = (const float*)d_in[7];
    const float* a_dst2 = (const float*)d_in[8];
    const float* b2     = (const float*)d_in[9];

    const int N = in_sizes[0] / 128;   // 50000
    const int E = in_sizes[1] / 2;     // 800000
    const int F_IN = 128, H = 256, F_OUT = 128;
    const int EA = E + N;

    const int* srcE = eidx;
    const int* dstE = eidx + E;

    // ---- workspace layout ----
    unsigned short* xbf    = (unsigned short*)d_ws;                 // N*128 bf16
    unsigned short* aggx   = xbf + (size_t)N * F_IN;                // N*128 bf16
    unsigned short* g1     = aggx + (size_t)N * F_IN;               // N*256 bf16
    unsigned short* h2bf   = g1 + (size_t)N * H;                    // N*128 bf16
    float*          sbuf   = (float*)(h2bf + (size_t)N * F_OUT);    // N
    float*          dbuf   = sbuf + N;                              // N
    float*          w_s1   = dbuf + N;                              // 128
    float*          w_d1   = w_s1 + F_IN;                           // 128
    unsigned short* w1T    = (unsigned short*)(w_d1 + F_IN);        // 256*128
    unsigned short* w2T    = w1T + 32768;                           // 128*256
    int*            rowptr = (int*)(w2T + 32768);                   // N+1
    int*            histG  = rowptr + (N + 1);                      // NB*NBUCKET
    int*            colSum = histG + NB * NBUCKET;                  // NBUCKET
    int*            ssrc   = colSum + NBUCKET;                      // E+N
    unsigned*       packed = (unsigned*)(ssrc + EA);                // E+N

    float* out = (float*)d_out;
    const int xblocks = (N * 64 + 255) / 256;   // 12500

    // 1) bucket histograms + weight prep
    hist_wprep_k<<<NB + 288, 256, 0, stream>>>(
        dstE, W1, W2, a_src1, a_dst1, histG, w1T, w2T, w_s1, w_d1, E, N);
    // 2) column scan + xprep
    colscan_xprep_k<<<NBUCKET / 4 + xblocks, 256, 0, stream>>>(
        histG, colSum, x, w_s1, w_d1, xbf, sbuf, dbuf, N);
    // 3) scatter into bucket-grouped order
    bscatter_k<<<NB, 256, 0, stream>>>(srcE, dstE, histG, colSum, packed, E, N);
    // 4) per-bucket counting sort -> ssrc + rowptr
    bsort_k<<<NBUCKET, 256, 0, stream>>>(packed, colSum, ssrc, rowptr, EA, N);

    // 5) layer-1 gather
    {
        int nb = (N + 3) / 4;
        node_gather_k<true><<<nb, 256, 0, stream>>>(
            rowptr, ssrc, sbuf, dbuf, xbf, nullptr, aggx, nullptr, N);
    }
    // 6) GEMM1 (relu+bias epilogue)
    {
        dim3 gg((N + 127) / 128, H / 128);
        gemm_bf16<128, 256, 1><<<gg, 256, 0, stream>>>(
            aggx, w1T, g1, b1, nullptr, nullptr, nullptr, nullptr, N);
    }
    // 7) GEMM2 (+ in-epilogue layer-2 rowdots)
    {
        dim3 gg((N + 127) / 128, 1);
        gemm_bf16<256, 128, 2><<<gg, 256, 0, stream>>>(
            g1, w2T, h2bf, nullptr, a_src2, a_dst2, sbuf, dbuf, N);
    }
    // 8) layer-2 gather (final output)
    {
        int nb = (N + 3) / 4;
        node_gather_k<false><<<nb, 256, 0, stream>>>(
            rowptr, ssrc, sbuf, dbuf, h2bf, b2, nullptr, out, N);
    }
}